// Round 4
// baseline (550.480 us; speedup 1.0000x reference)
//
#include <hip/hip_runtime.h>
#include <stdint.h>

// VectorQuantizer: z[32768,512] f32, weight[8192,512] f32 ->
//   out[0 .. 32768*512) = z_q = weight[argmin_k ||z-e_k||^2]  (exact fp32 rows)
//   out[32768*512]      = perplexity
//
// Pipeline:
//  1) k_prep_z: bf16(-2z); k_prep_w: bf16(w) + exact f32 row norms c_k
//  2) k_phase1: 256x256-tile 8-wave deep-pipelined bf16 MFMA (T2+T3+T4+T5):
//     acc init = c_k, accumulate (-2z).e -> d = c - 2 z.e directly.
//     Per token keep top-2 packed keys (quantized d | 13-bit code) per
//     128 cells (cell = (split,wcN,col), 64 codes each) -> slotbuf
//  3) k_select: global min; margin candidates re-ranked with exact f64 dots
//     (cells with both entries in margin fully rescanned); idx + histogram
//  4) k_gather: z_q rows ; k_perp: perplexity
//
// ws layout (bytes): zb@0 32MB | wb@33554432 8MB | cnorm@41943040 32KB |
//   slot@41975808 32MB | idx@75530240 128KB | counts@75661312 32KB

#define NTOK 32768
#define NE   8192
#define DIM  512
#define MARGIN 4.0f

typedef __attribute__((ext_vector_type(8))) short bf16x8;
typedef __attribute__((ext_vector_type(4))) float f32x4;

#define LGKM0  asm volatile("s_waitcnt lgkmcnt(0)" ::: "memory")
#define SBAR   __builtin_amdgcn_s_barrier()
#define SCHED0 __builtin_amdgcn_sched_barrier(0)

__device__ __forceinline__ unsigned int f2bf1(float x) {
  unsigned int u = __float_as_uint(x);
  return (u + 0x7FFFu + ((u >> 16) & 1u)) >> 16;
}
__device__ __forceinline__ unsigned int packbf2(float lo, float hi) {
  return f2bf1(lo) | (f2bf1(hi) << 16);
}

__device__ __forceinline__ void gl_lds16(const void* g, void* l) {
  __builtin_amdgcn_global_load_lds(
      (const __attribute__((address_space(1))) void*)g,
      (__attribute__((address_space(3))) void*)l, 16, 0, 0);
}

__global__ void k_prep_z(const float* __restrict__ z, unsigned int* __restrict__ zb) {
  int i = blockIdx.x * 256 + threadIdx.x;  // one thread per 8 floats
  const float4* zp = (const float4*)z + (size_t)i * 2;
  float4 a = zp[0], b = zp[1];
  uint4 o;  // store bf16(-2z): exact 2x scaling, same rounding as bf16(z)
  o.x = packbf2(-2.f * a.x, -2.f * a.y); o.y = packbf2(-2.f * a.z, -2.f * a.w);
  o.z = packbf2(-2.f * b.x, -2.f * b.y); o.w = packbf2(-2.f * b.z, -2.f * b.w);
  ((uint4*)zb)[i] = o;
}

__global__ void k_prep_w(const float* __restrict__ w, unsigned int* __restrict__ wb,
                         float* __restrict__ cnorm) {
  int row  = blockIdx.x * 4 + (threadIdx.x >> 6);  // one wave per code row
  int lane = threadIdx.x & 63;
  const float4* wp = (const float4*)(w + (size_t)row * DIM) + lane * 2;
  float4 a = wp[0], b = wp[1];
  uint4 o;
  o.x = packbf2(a.x, a.y); o.y = packbf2(a.z, a.w);
  o.z = packbf2(b.x, b.y); o.w = packbf2(b.z, b.w);
  ((uint4*)wb)[(size_t)row * 64 + lane] = o;
  float s = a.x * a.x + a.y * a.y + a.z * a.z + a.w * a.w
          + b.x * b.x + b.y * b.y + b.z * b.z + b.w * b.w;
#pragma unroll
  for (int m = 1; m < 64; m <<= 1) s += __shfl_xor(s, m);
  if (lane == 0) cnorm[row] = s;
}

// 512 thr = 8 waves (wrM in 0..3, wcN in 0..1); tile 256 tok x 256 codes.
// Wave tile 64x128 = 4mi x 8fj frags of 16x16x32. BK=64, dbuf LDS 128KB.
// grid 512 = 128 tb x 4 splits (2048 codes = 8 ct tiles each), XCD-chunked.
__global__ void __launch_bounds__(512, 2) k_phase1(
    const unsigned short* __restrict__ zb, const unsigned short* __restrict__ wb,
    const float* __restrict__ cnorm, float* __restrict__ slotbuf) {
  __shared__ char Ab[2][32768];  // [sel][256 rows][64 k] bf16, xor-swizzled
  __shared__ char Bb[2][32768];

  const int tid  = threadIdx.x;
  const int lane = tid & 63;
  const int wv   = tid >> 6;
  const int wrM  = wv >> 1;   // 0..3  (token quarter)
  const int wcN  = wv & 1;    // 0..1  (code half)
  const int swz   = (blockIdx.x & 7) * 64 + (blockIdx.x >> 3);
  const int split = swz >> 7;   // 0..3
  const int tb    = swz & 127;  // 0..127
  const int l15  = lane & 15;
  // staging source col-byte pre-swizzle: dest (row, col ^ ((row&7)<<4)), row&7 = lane>>3
  const int cbsw = ((lane & 7) ^ (lane >> 3)) << 4;

  const char* srcA = (const char*)zb + (size_t)(tb * 256 + wv * 8 + (lane >> 3)) * 1024 + cbsw;
  const char* srcB = (const char*)wb + (size_t)(split * 2048 + wv * 8 + (lane >> 3)) * 1024 + cbsw;

  // frag read col-bytes (row&7 == l15&7 for all frag rows)
  const int csw0 = (((lane >> 4) << 4)) ^ ((lane & 7) << 4);
  const int csw1 = (64 + ((lane >> 4) << 4)) ^ ((lane & 7) << 4);
  int arow[4], brow[8];
#pragma unroll
  for (int mi = 0; mi < 4; ++mi) arow[mi] = (wrM * 64 + mi * 16 + l15) << 7;
#pragma unroll
  for (int fj = 0; fj < 8; ++fj) brow[fj] = (wcN * 128 + fj * 16 + l15) << 7;

  const float BIG = 3.0e38f;
  float m1s[4][4], m2s[4][4];
#pragma unroll
  for (int mi = 0; mi < 4; ++mi)
#pragma unroll
    for (int r = 0; r < 4; ++r) { m1s[mi][r] = BIG; m2s[mi][r] = BIG; }

  const unsigned int KMASK = 0xFFFFE000u;

  // prologue: stage step 0 (ct=0, kc=0) into sel 0
#pragma unroll
  for (int r = 0; r < 4; ++r) gl_lds16(srcA + r * 65536, &Ab[0][r * 8192 + wv * 1024]);
#pragma unroll
  for (int r = 0; r < 4; ++r) gl_lds16(srcB + r * 65536, &Bb[0][r * 8192 + wv * 1024]);

  for (int ct = 0; ct < 8; ++ct) {
    const int codebase = split * 2048 + ct * 256 + wcN * 128 + l15;
    float cf[8];
#pragma unroll
    for (int fj = 0; fj < 8; ++fj) cf[fj] = cnorm[codebase + fj * 16];
    f32x4 acc[4][8];
#pragma unroll
    for (int mi = 0; mi < 4; ++mi)
#pragma unroll
      for (int fj = 0; fj < 8; ++fj) {
        f32x4 v = {cf[fj], cf[fj], cf[fj], cf[fj]};
        acc[mi][fj] = v;  // d = c + (-2z).e accumulated by MFMA
      }

    for (int kc = 0; kc < 8; ++kc) {
      const int s = ct * 8 + kc;
      const int sel = s & 1, tsel = sel ^ 1;
      const int s1 = s + 1;
      const bool ok = (s1 < 64);
      const int kc1 = s1 & 7, ct1 = s1 >> 3;
      const int aof = kc1 * 128;
      const int bof = ct1 * 262144 + kc1 * 128;
      char* dA = &Ab[tsel][wv * 1024];
      char* dB = &Bb[tsel][wv * 1024];
      const char* Ac = &Ab[sel][0];
      const char* Bc = &Bb[sel][0];

      // entry: issue first prefetch pair for s+1, counted wait for s's tile
      if (ok) { gl_lds16(srcA + aof, dA); gl_lds16(srcA + aof + 65536, dA + 8192); }
      if (ok) { asm volatile("s_waitcnt vmcnt(2)" ::: "memory"); }
      else    { asm volatile("s_waitcnt vmcnt(0)" ::: "memory"); }
      SBAR;

      // ---- phase 0: read a[0..1], b[0..3]; mfma (mi 0-1 x fj 0-3)
      bf16x8 a0[2][2], b0[4][2];
#pragma unroll
      for (int mi = 0; mi < 2; ++mi) {
        a0[mi][0] = *(const bf16x8*)(Ac + arow[mi] + csw0);
        a0[mi][1] = *(const bf16x8*)(Ac + arow[mi] + csw1);
      }
#pragma unroll
      for (int fj = 0; fj < 4; ++fj) {
        b0[fj][0] = *(const bf16x8*)(Bc + brow[fj] + csw0);
        b0[fj][1] = *(const bf16x8*)(Bc + brow[fj] + csw1);
      }
      if (ok) { gl_lds16(srcA + aof + 131072, dA + 16384); gl_lds16(srcA + aof + 196608, dA + 24576); }
      SBAR; LGKM0; SCHED0;
      __builtin_amdgcn_s_setprio(1);
#pragma unroll
      for (int mi = 0; mi < 2; ++mi)
#pragma unroll
        for (int fj = 0; fj < 4; ++fj) {
          acc[mi][fj] = __builtin_amdgcn_mfma_f32_16x16x32_bf16(a0[mi][0], b0[fj][0], acc[mi][fj], 0, 0, 0);
          acc[mi][fj] = __builtin_amdgcn_mfma_f32_16x16x32_bf16(a0[mi][1], b0[fj][1], acc[mi][fj], 0, 0, 0);
        }
      __builtin_amdgcn_s_setprio(0);
      SBAR;

      // ---- phase 1: read a[2..3]; mfma (mi 2-3 x fj 0-3)
      bf16x8 a1[2][2];
#pragma unroll
      for (int mi = 0; mi < 2; ++mi) {
        a1[mi][0] = *(const bf16x8*)(Ac + arow[mi + 2] + csw0);
        a1[mi][1] = *(const bf16x8*)(Ac + arow[mi + 2] + csw1);
      }
      if (ok) { gl_lds16(srcB + bof, dB); gl_lds16(srcB + bof + 65536, dB + 8192); }
      SBAR; LGKM0; SCHED0;
      __builtin_amdgcn_s_setprio(1);
#pragma unroll
      for (int mi = 0; mi < 2; ++mi)
#pragma unroll
        for (int fj = 0; fj < 4; ++fj) {
          acc[mi + 2][fj] = __builtin_amdgcn_mfma_f32_16x16x32_bf16(a1[mi][0], b0[fj][0], acc[mi + 2][fj], 0, 0, 0);
          acc[mi + 2][fj] = __builtin_amdgcn_mfma_f32_16x16x32_bf16(a1[mi][1], b0[fj][1], acc[mi + 2][fj], 0, 0, 0);
        }
      __builtin_amdgcn_s_setprio(0);
      SBAR;

      // ---- phase 2: read b[4..7]; mfma (mi 2-3 x fj 4-7)
      bf16x8 b1[4][2];
#pragma unroll
      for (int fj = 0; fj < 4; ++fj) {
        b1[fj][0] = *(const bf16x8*)(Bc + brow[fj + 4] + csw0);
        b1[fj][1] = *(const bf16x8*)(Bc + brow[fj + 4] + csw1);
      }
      if (ok) { gl_lds16(srcB + bof + 131072, dB + 16384); gl_lds16(srcB + bof + 196608, dB + 24576); }
      SBAR; LGKM0; SCHED0;
      __builtin_amdgcn_s_setprio(1);
#pragma unroll
      for (int mi = 0; mi < 2; ++mi)
#pragma unroll
        for (int fj = 0; fj < 4; ++fj) {
          acc[mi + 2][fj + 4] = __builtin_amdgcn_mfma_f32_16x16x32_bf16(a1[mi][0], b1[fj][0], acc[mi + 2][fj + 4], 0, 0, 0);
          acc[mi + 2][fj + 4] = __builtin_amdgcn_mfma_f32_16x16x32_bf16(a1[mi][1], b1[fj][1], acc[mi + 2][fj + 4], 0, 0, 0);
        }
      __builtin_amdgcn_s_setprio(0);
      SBAR;

      // ---- phase 3: re-read a[0..1]; mfma (mi 0-1 x fj 4-7)
      bf16x8 a2[2][2];
#pragma unroll
      for (int mi = 0; mi < 2; ++mi) {
        a2[mi][0] = *(const bf16x8*)(Ac + arow[mi] + csw0);
        a2[mi][1] = *(const bf16x8*)(Ac + arow[mi] + csw1);
      }
      SBAR; LGKM0; SCHED0;
      __builtin_amdgcn_s_setprio(1);
#pragma unroll
      for (int mi = 0; mi < 2; ++mi)
#pragma unroll
        for (int fj = 0; fj < 4; ++fj) {
          acc[mi][fj + 4] = __builtin_amdgcn_mfma_f32_16x16x32_bf16(a2[mi][0], b1[fj][0], acc[mi][fj + 4], 0, 0, 0);
          acc[mi][fj + 4] = __builtin_amdgcn_mfma_f32_16x16x32_bf16(a2[mi][1], b1[fj][1], acc[mi][fj + 4], 0, 0, 0);
        }
      __builtin_amdgcn_s_setprio(0);
      SBAR;
    }

    // epilogue: pack (quantized d | code), incremental top-2 insert per row
#pragma unroll
    for (int mi = 0; mi < 4; ++mi) {
#pragma unroll
      for (int r = 0; r < 4; ++r) {
        float M1 = m1s[mi][r], M2 = m2s[mi][r];
#pragma unroll
        for (int fj = 0; fj < 8; ++fj) {
          float kf = __uint_as_float((__float_as_uint(acc[mi][fj][r]) & KMASK) |
                                     (unsigned)(codebase + fj * 16));
          M2 = fminf(M2, fmaxf(M1, kf));
          M1 = fminf(M1, kf);
        }
        m1s[mi][r] = M1; m2s[mi][r] = M2;
      }
    }
  }

  const int cell = split * 32 + wcN * 16 + l15;
#pragma unroll
  for (int mi = 0; mi < 4; ++mi) {
#pragma unroll
    for (int r = 0; r < 4; ++r) {
      int token = tb * 256 + wrM * 64 + mi * 16 + (lane >> 4) * 4 + r;
      float2* p = (float2*)(slotbuf + (size_t)token * 256);
      p[cell] = make_float2(m1s[mi][r], m2s[mi][r]);
    }
  }
}

// one wave per token; exact f64 re-rank of margin candidates
__global__ void k_select(const float* __restrict__ slotbuf, const float* __restrict__ z,
                         const float* __restrict__ w, int* __restrict__ idxb,
                         unsigned int* __restrict__ counts) {
  const int lane = threadIdx.x & 63;
  const int t = blockIdx.x * 4 + (threadIdx.x >> 6);

  float4 e = *(const float4*)(slotbuf + (size_t)t * 256 + lane * 4);
  float p0 = e.x, p1 = e.y, p2 = e.z, p3 = e.w;  // cells 2*lane (m1,m2), 2*lane+1 (m1,m2)
  float pk = fminf(fminf(p0, p1), fminf(p2, p3));
#pragma unroll
  for (int m = 1; m < 64; m <<= 1) pk = fminf(pk, __shfl_xor(pk, m));
  const unsigned int mb = __float_as_uint(pk);
  int best = (int)(mb & 0x1FFFu);
  const float thr = __uint_as_float(mb & 0xFFFFE000u) + MARGIN;

  const unsigned int KM = 0xFFFFE000u;
  bool f0 = __uint_as_float(__float_as_uint(p0) & KM) < thr;  // cell 2lane m1
  bool f1 = __uint_as_float(__float_as_uint(p1) & KM) < thr;  // cell 2lane m2
  bool f2 = __uint_as_float(__float_as_uint(p2) & KM) < thr;  // cell 2lane+1 m1
  bool f3 = __uint_as_float(__float_as_uint(p3) & KM) < thr;  // cell 2lane+1 m2
  unsigned long long b0 = __ballot(f0), b1 = __ballot(f1);
  unsigned long long b2 = __ballot(f2), b3 = __ballot(f3);
  int nc = __popcll(b0) + __popcll(b1) + __popcll(b2) + __popcll(b3);

  if (nc > 1) {
    const float4* zp = (const float4*)(z + (size_t)t * DIM) + lane * 2;
    float4 za = zp[0], zc = zp[1];
    double bestd = 1e300;
    int besti = NE;

    auto eval = [&](int code) {
      const float4* wp = (const float4*)(w + (size_t)code * DIM) + lane * 2;
      float4 wa = wp[0], wv2 = wp[1];
      double d = (double)wa.x * ((double)wa.x - 2.0 * (double)za.x)
               + (double)wa.y * ((double)wa.y - 2.0 * (double)za.y)
               + (double)wa.z * ((double)wa.z - 2.0 * (double)za.z)
               + (double)wa.w * ((double)wa.w - 2.0 * (double)za.w)
               + (double)wv2.x * ((double)wv2.x - 2.0 * (double)zc.x)
               + (double)wv2.y * ((double)wv2.y - 2.0 * (double)zc.y)
               + (double)wv2.z * ((double)wv2.z - 2.0 * (double)zc.z)
               + (double)wv2.w * ((double)wv2.w - 2.0 * (double)zc.w);
#pragma unroll
      for (int m = 1; m < 64; m <<= 1) d += __shfl_xor(d, m);
      if (d < bestd || (d == bestd && code < besti)) { bestd = d; besti = code; }
    };
    // cell = (split, wcN, col): codes sp*2048 + ct*256 + wcN*128 + fj*16 + col
    auto scan_cell = [&](int cid) {
      int sp = cid >> 5, wcc = (cid >> 4) & 1, col = cid & 15;
      int base = sp * 2048 + wcc * 128 + col;
      for (int ctt = 0; ctt < 8; ++ctt)
        for (int fj = 0; fj < 8; ++fj)
          eval(base + ctt * 256 + fj * 16);
    };

    int i0 = (int)(__float_as_uint(p0) & 0x1FFFu);
    int i1 = (int)(__float_as_uint(p1) & 0x1FFFu);
    int i2 = (int)(__float_as_uint(p2) & 0x1FFFu);
    int i3 = (int)(__float_as_uint(p3) & 0x1FFFu);
    unsigned long long bm;
    bm = b0; while (bm) { int s = __ffsll(bm) - 1; bm &= bm - 1; eval(__shfl(i0, s)); }
    bm = b1; while (bm) { int s = __ffsll(bm) - 1; bm &= bm - 1; eval(__shfl(i1, s)); }
    bm = b2; while (bm) { int s = __ffsll(bm) - 1; bm &= bm - 1; eval(__shfl(i2, s)); }
    bm = b3; while (bm) { int s = __ffsll(bm) - 1; bm &= bm - 1; eval(__shfl(i3, s)); }
    unsigned long long h0 = __ballot(f0 && f1);
    unsigned long long h1 = __ballot(f2 && f3);
    bm = h0; while (bm) { int s = __ffsll(bm) - 1; bm &= bm - 1; scan_cell(2 * s); }
    bm = h1; while (bm) { int s = __ffsll(bm) - 1; bm &= bm - 1; scan_cell(2 * s + 1); }
    best = besti;
  }
  if (lane == 0) {
    idxb[t] = best;
    atomicAdd(&counts[best], 1u);
  }
}

__global__ void k_gather(const float* __restrict__ w, const int* __restrict__ idxb,
                         float* __restrict__ out) {
  int n = blockIdx.x * 2 + (threadIdx.x >> 7);
  int j = threadIdx.x & 127;
  int k = idxb[n];
  ((float4*)out)[(size_t)n * 128 + j] = ((const float4*)w)[(size_t)k * 128 + j];
}

__global__ void k_perp(const unsigned int* __restrict__ counts, float* __restrict__ out) {
  __shared__ float red[16];
  float s = 0.f;
  for (int k = threadIdx.x; k < NE; k += 1024) {
    float p = (float)counts[k] * (1.0f / (float)NTOK);
    s += p * logf(p + 1e-10f);
  }
#pragma unroll
  for (int m = 1; m < 64; m <<= 1) s += __shfl_xor(s, m);
  int lane = threadIdx.x & 63, wv = threadIdx.x >> 6;
  if (lane == 0) red[wv] = s;
  __syncthreads();
  if (threadIdx.x == 0) {
    float tot = 0.f;
    for (int i = 0; i < 16; ++i) tot += red[i];
    out[(size_t)NTOK * DIM] = expf(-tot);
  }
}

extern "C" void kernel_launch(void* const* d_in, const int* in_sizes, int n_in,
                              void* d_out, int out_size, void* d_ws, size_t ws_size,
                              hipStream_t stream) {
  const float* z = (const float*)d_in[0];
  const float* w = (const float*)d_in[1];
  float* out = (float*)d_out;
  char* ws = (char*)d_ws;

  unsigned int* zb      = (unsigned int*)(ws);
  unsigned int* wb      = (unsigned int*)(ws + 33554432);
  float*        cnorm   = (float*)(ws + 41943040);
  float*        slotbuf = (float*)(ws + 41975808);
  int*          idxb    = (int*)(ws + 75530240);
  unsigned int* counts  = (unsigned int*)(ws + 75661312);

  k_prep_z<<<8192, 256, 0, stream>>>(z, zb);
  k_prep_w<<<2048, 256, 0, stream>>>(w, wb, cnorm);
  k_phase1<<<512, 512, 0, stream>>>((const unsigned short*)zb, (const unsigned short*)wb,
                                    cnorm, slotbuf);
  hipMemsetAsync(counts, 0, NE * sizeof(unsigned int), stream);
  k_select<<<8192, 256, 0, stream>>>(slotbuf, z, w, idxb, counts);
  k_gather<<<16384, 256, 0, stream>>>(w, idxb, out);
  k_perp<<<1, 1024, 0, stream>>>(counts, out);
}